// Round 2
// baseline (383.458 us; speedup 1.0000x reference)
//
#include <hip/hip_runtime.h>
#include <math.h>
#include <limits.h>

// ---- problem constants ----
#define C_IN 256
#define HM_H 136
#define HM_W 240
#define HM_N (HM_H * HM_W)      // 32640
#define MB   64
#define MH   272
#define MW   480
#define MN   (MH * MW)          // 130560
#define NP   134
#define NI   4
#define HID  64

// d_out layout (floats): scores[4] | inds[4] | regs0[4*MN] | masks0[4*MN] | feat[4*480*2]
#define REG_OFF   8
#define MASK_OFF  (8 + NI * MN)
#define FEAT_OFF  (8 + 2 * NI * MN)

// ws layout (floats): hm[32640] | cand_v[512]+cand_i[512] | gp[536] | wt @ 65824
#define WS_HM   0
#define WS_CV   HM_N
#define WS_CI   (HM_N + 512)
#define WS_GP   (2 * HM_N)
#define WS_WT_F 65824

typedef float  f32x4  __attribute__((ext_vector_type(4)));
typedef short  bf16x8 __attribute__((ext_vector_type(8)));
typedef unsigned short u16x8 __attribute__((ext_vector_type(8)));

__device__ __forceinline__ unsigned short f2bf(float f) {
  unsigned int u = __float_as_uint(f);
  u += 0x7FFFu + ((u >> 16) & 1u);
  return (unsigned short)(u >> 16);
}
__device__ __forceinline__ float b2f(unsigned short h) {
  return __uint_as_float(((unsigned int)h) << 16);
}

// ------------------------------------------------------------------
// K0: merged weight-prep + heatmap.
// ------------------------------------------------------------------
__global__ void k_prep(const float* __restrict__ mb_w, unsigned short* __restrict__ wt,
                       const float* __restrict__ out1, const float* __restrict__ hm_w,
                       const float* __restrict__ hm_b, float* __restrict__ ws_hm) {
  __shared__ float part[4][64];
  if (blockIdx.x < 576) {
    int idx = blockIdx.x * 256 + threadIdx.x;     // 147456 total
    int j    = idx & 7;
    int lane = (idx >> 3) & 63;
    int nt   = (idx >> 9) & 3;
    int gt   = idx >> 11;
    int t    = gt % 9;
    int g    = gt / 9;
    int n = nt * 16 + (lane & 15);
    int c = g * 32 + (lane >> 4) * 8 + j;
    wt[idx] = f2bf(mb_w[(n * C_IN + c) * 9 + t]);
  } else {
    int b = blockIdx.x - 576, t = threadIdx.x;
    int cg = t >> 6, pl = t & 63;
    int p = b * 64 + pl;                         // 510*64 = 32640
    float s = 0.f;
    #pragma unroll 16
    for (int c = 0; c < 64; ++c)
      s += hm_w[cg * 64 + c] * out1[(cg * 64 + c) * HM_N + p];
    part[cg][pl] = s;
    __syncthreads();
    if (t < 64) {
      float tot = part[0][t] + part[1][t] + part[2][t] + part[3][t] + hm_b[0];
      float sig = 1.f / (1.f + expf(-tot));
      sig = fminf(fmaxf(sig, 1e-4f), 1.f - 1e-4f);
      ws_hm[b * 64 + t] = sig;
    }
  }
}

// ------------------------------------------------------------------
// top-4 list merge helpers
// ------------------------------------------------------------------
__device__ __forceinline__ bool better(float av, int ai, float bv, int bi) {
  return (av > bv) || (av == bv && ai < bi);
}

template<int NTHR>
__device__ void top4_tree(float* sv, int* si, int t) {
  for (int s = NTHR / 2; s >= 1; s >>= 1) {
    if (t < s) {
      float a[4], b[4]; int ai[4], bj[4];
      #pragma unroll
      for (int k = 0; k < 4; ++k) {
        a[k] = sv[t * 4 + k];        ai[k] = si[t * 4 + k];
        b[k] = sv[(t + s) * 4 + k];  bj[k] = si[(t + s) * 4 + k];
      }
      float ov[4]; int oi[4];
      int i = 0, j = 0;
      #pragma unroll
      for (int k = 0; k < 4; ++k) {
        if (better(a[i], ai[i], b[j], bj[j])) { ov[k] = a[i]; oi[k] = ai[i]; ++i; }
        else                                   { ov[k] = b[j]; oi[k] = bj[j]; ++j; }
      }
      #pragma unroll
      for (int k = 0; k < 4; ++k) { sv[t * 4 + k] = ov[k]; si[t * 4 + k] = oi[k]; }
    }
    __syncthreads();
  }
}

// ------------------------------------------------------------------
// K2a: fused NMS + per-block top-4 (128 blocks x 255 pixels)
// ------------------------------------------------------------------
__global__ void k_nms_top(const float* __restrict__ ws_hm, float* __restrict__ candv,
                          int* __restrict__ candi) {
  __shared__ float sv[256 * 4];
  __shared__ int   si[256 * 4];
  int b = blockIdx.x, t = threadIdx.x;
  float v = -1.f; int idx = INT_MAX;
  if (t < 255) {
    int p = b * 255 + t;
    int y = p / HM_W, x = p - y * HM_W;
    float c = ws_hm[p], m = c;
    #pragma unroll
    for (int dy = -1; dy <= 1; ++dy)
      #pragma unroll
      for (int dx = -1; dx <= 1; ++dx) {
        int yy = y + dy, xx = x + dx;
        if (yy >= 0 && yy < HM_H && xx >= 0 && xx < HM_W)
          m = fmaxf(m, ws_hm[yy * HM_W + xx]);
      }
    v = (c == m) ? c : 0.f;
    idx = p;
  }
  sv[t * 4] = v; si[t * 4] = idx;
  #pragma unroll
  for (int k = 1; k < 4; ++k) { sv[t * 4 + k] = -1.f; si[t * 4 + k] = INT_MAX; }
  __syncthreads();
  top4_tree<256>(sv, si, t);
  if (t == 0) {
    #pragma unroll
    for (int k = 0; k < 4; ++k) { candv[b * 4 + k] = sv[k]; candi[b * 4 + k] = si[k]; }
  }
}

// ------------------------------------------------------------------
// K3: redundant final top-k merge + gen_params. Block i -> instance i.
// ------------------------------------------------------------------
__global__ void k_gen(const float* __restrict__ candv, const int* __restrict__ candi,
                      const float* __restrict__ out1, const float* __restrict__ params_w,
                      const float* __restrict__ params_b, float* __restrict__ ws_gp,
                      float* __restrict__ d_out) {
  __shared__ float sv[128 * 4];
  __shared__ int   si[128 * 4];
  __shared__ float col[C_IN];
  int t = threadIdx.x, i = blockIdx.x;
  if (t < 128) {
    #pragma unroll
    for (int k = 0; k < 4; ++k) { sv[t * 4 + k] = candv[t * 4 + k]; si[t * 4 + k] = candi[t * 4 + k]; }
  }
  __syncthreads();
  top4_tree<128>(sv, si, t);
  if (i == 0 && t < 4) {
    d_out[t]     = sv[t];
    d_out[4 + t] = (float)si[t];
  }
  int p = si[i];
  col[t] = out1[t * HM_N + p];
  __syncthreads();
  if (t < NP) {
    float s = params_b[t];
    #pragma unroll 8
    for (int c = 0; c < C_IN; ++c) s += params_w[t * C_IN + c] * col[c];
    ws_gp[i * NP + t] = s;
  }
}

// ------------------------------------------------------------------
// K4: MFMA implicit-GEMM conv.
// v3: 8 waves = 4 pixel-groups x 2 channel-halves (acc[4][2]);
//     weight loads issued BEFORE staging loads (vmcnt FIFO decoupling,
//     sched_barrier-fenced); staging = 400 units of 8 channels ->
//     full-granule ds_write_b128 with parity-spread slot map:
//     ushort_off = (pix>>1)*64 + ((g16^w2)<<4) + ((pix^row)&1)*8,
//     w2 = (pix ^ (pix>>2)) & 3.  (x-half +512 trick preserved.)
// ------------------------------------------------------------------
#define RP   36                 // stored x positions per row (gx0-1 .. gx0+34)
#define BUFU (10 * RP * 32)     // 11520 ushorts = 23040 B per buffer

__device__ __forceinline__ void stage_store8(unsigned short* buf, const f32x4* dq,
                                             bool gv, const int* lw, unsigned sm) {
  #pragma unroll
  for (int e = 0; e < 4; ++e) if ((sm >> e) & 1u) {
    u16x8 v;
    #pragma unroll
    for (int j = 0; j < 8; ++j) v[j] = f2bf(gv ? dq[j][e] : 0.f);
    *(u16x8*)(buf + lw[e]) = v;
  }
}

#define MFMA_TAPS(B, T0)                                                         \
  _Pragma("unroll")                                                              \
  for (int tt = 0; tt < 3; ++tt) {                                               \
    unsigned pk = lrdp[(T0) + tt];                                               \
    const unsigned short* c0 = cur + (pk & 0xFFFFu);                             \
    const unsigned short* c1 = cur + (pk >> 16);                                 \
    bf16x8 a0 = *(const bf16x8*)c0;                                              \
    bf16x8 a1 = *(const bf16x8*)(c0 + 512);                                      \
    bf16x8 a2 = *(const bf16x8*)c1;                                              \
    bf16x8 a3 = *(const bf16x8*)(c1 + 512);                                      \
    acc[0][0] = __builtin_amdgcn_mfma_f32_16x16x32_bf16(a0, B[tt][0], acc[0][0], 0, 0, 0); \
    acc[0][1] = __builtin_amdgcn_mfma_f32_16x16x32_bf16(a0, B[tt][1], acc[0][1], 0, 0, 0); \
    acc[1][0] = __builtin_amdgcn_mfma_f32_16x16x32_bf16(a1, B[tt][0], acc[1][0], 0, 0, 0); \
    acc[1][1] = __builtin_amdgcn_mfma_f32_16x16x32_bf16(a1, B[tt][1], acc[1][1], 0, 0, 0); \
    acc[2][0] = __builtin_amdgcn_mfma_f32_16x16x32_bf16(a2, B[tt][0], acc[2][0], 0, 0, 0); \
    acc[2][1] = __builtin_amdgcn_mfma_f32_16x16x32_bf16(a2, B[tt][1], acc[2][1], 0, 0, 0); \
    acc[3][0] = __builtin_amdgcn_mfma_f32_16x16x32_bf16(a3, B[tt][0], acc[3][0], 0, 0, 0); \
    acc[3][1] = __builtin_amdgcn_mfma_f32_16x16x32_bf16(a3, B[tt][1], acc[3][1], 0, 0, 0); \
  }

__global__ __launch_bounds__(512, 4) void k_conv_mfma(
    const float* __restrict__ out0, const unsigned short* __restrict__ wt,
    const float* __restrict__ mb_b, const float* __restrict__ ws_gp,
    float* __restrict__ d_out) {
  __shared__ unsigned short smem[2 * BUFU];   // 46080 B

  int tid  = threadIdx.x;
  int lane = tid & 63;
  int wv   = tid >> 6;       // wave 0..7
  int n15  = lane & 15;
  int kq   = lane >> 4;
  int pg   = wv & 3;         // pixel group (64 px)
  int ce   = wv >> 2;        // channel half (32 ch)
  int gx0 = blockIdx.x * 32, gy0 = blockIdx.y * 8;

  // --- staging descriptor: 400 units of (co8, row, qx); unit = 8 float4 -> 4 b128 ---
  bool act = tid < 400;
  int u    = act ? tid : 0;
  int co8  = u / 100;                 // 0..3  (8-channel group)
  int rem  = u - co8 * 100;
  int row  = rem / 10;                // 0..9  (stored row)
  int qx   = rem - row * 10;          // 0..9  (x quad)
  int iy   = gy0 + row - 1;
  int ixq  = gx0 + 4 * qx - 4;        // 16B-aligned quad
  bool gvld = act && (iy >= 0) && (iy < MH) && (ixq >= 0) && (ixq + 3 < MW);
  int goff  = gvld ? (co8 * 8 * MN + iy * MW + ixq) : 0;
  int lws[4]; unsigned smask = 0;
  #pragma unroll
  for (int e = 0; e < 4; ++e) {
    int sx = 4 * qx - 3 + e;          // stored x index
    bool sv = act && (sx >= 0) && (sx < RP);
    int pixw = row * RP + (sv ? sx : 0);
    int w2 = (pixw ^ (pixw >> 2)) & 3;
    int q  = (pixw ^ row) & 1;
    lws[e] = (pixw >> 1) * 64 + ((co8 ^ w2) << 4) + q * 8;
    if (sv) smask |= (1u << e);
  }

  // --- A-frag LDS read offsets: packed (d0 | d1<<16) per tap; +512 = x-half ---
  unsigned lrdp[9];
  #pragma unroll
  for (int t = 0; t < 9; ++t) {
    int ty = t / 3, tx = t - ty * 3;
    int sr0 = pg * 2 + ty;            // stored row for subtiles i=0,1
    int pix0 = sr0 * RP + n15 + tx;
    int w20 = (pix0 ^ (pix0 >> 2)) & 3;
    int q0  = (pix0 ^ sr0) & 1;
    unsigned o0 = (pix0 >> 1) * 64 + ((kq ^ w20) << 4) + q0 * 8;
    int sr1 = sr0 + 1;                // subtiles i=2,3
    int pix1 = sr1 * RP + n15 + tx;
    int w21 = (pix1 ^ (pix1 >> 2)) & 3;
    int q1  = (pix1 ^ sr1) & 1;
    unsigned o1 = (pix1 >> 1) * 64 + ((kq ^ w21) << 4) + q1 * 8;
    lrdp[t] = o0 | (o1 << 16);
  }

  // --- prologue: stage ch-group 0 into buf0 ---
  {
    f32x4 dq[8];
    const float* sp = out0 + goff;
    #pragma unroll
    for (int j = 0; j < 8; ++j) dq[j] = *(const f32x4*)(sp + j * MN);
    stage_store8(smem, dq, gvld, lws, smask);
  }
  __syncthreads();

  f32x4 acc[4][2];
  #pragma unroll
  for (int i = 0; i < 4; ++i)
    #pragma unroll
    for (int nt = 0; nt < 2; ++nt)
      acc[i][nt] = (f32x4){0.f, 0.f, 0.f, 0.f};

  #pragma unroll 1
  for (int g = 0; g < 8; ++g) {
    const unsigned short* cur = smem + (g & 1) * BUFU;
    unsigned short*       nxt = smem + ((g + 1) & 1) * BUFU;
    const float*          src = out0 + (g + 1) * (32 * MN);
    const unsigned short* wg_ = wt + g * (9 * 2048) + ce * 1024 + lane * 8;

    // B loads for taps 0..5 FIRST (L2-fast; must precede HBM staging in vmcnt FIFO)
    bf16x8 b0[3][2], b1[3][2];
    #pragma unroll
    for (int tt = 0; tt < 3; ++tt) {
      b0[tt][0] = *(const bf16x8*)(wg_ + tt * 2048);
      b0[tt][1] = *(const bf16x8*)(wg_ + tt * 2048 + 512);
    }
    #pragma unroll
    for (int tt = 0; tt < 3; ++tt) {
      b1[tt][0] = *(const bf16x8*)(wg_ + (3 + tt) * 2048);
      b1[tt][1] = *(const bf16x8*)(wg_ + (3 + tt) * 2048 + 512);
    }
    __builtin_amdgcn_sched_barrier(0);
    // HBM staging loads for next tile
    f32x4 dq[8];
    if (g < 7) {
      const float* sp = src + goff;
      #pragma unroll
      for (int j = 0; j < 8; ++j) dq[j] = *(const f32x4*)(sp + j * MN);
    }
    __builtin_amdgcn_sched_barrier(0);

    MFMA_TAPS(b0, 0)        // taps 0..2  (waits only B0: counted vmcnt)
    MFMA_TAPS(b1, 3)        // taps 3..5

    // B loads for taps 6..8, then the single HBM wait of this iteration
    bf16x8 b2[3][2];
    #pragma unroll
    for (int tt = 0; tt < 3; ++tt) {
      b2[tt][0] = *(const bf16x8*)(wg_ + (6 + tt) * 2048);
      b2[tt][1] = *(const bf16x8*)(wg_ + (6 + tt) * 2048 + 512);
    }
    if (g < 7) stage_store8(nxt, dq, gvld, lws, smask);

    MFMA_TAPS(b2, 6)        // taps 6..8

    __syncthreads();
  }

  // --- epilogue: bias+relu, acc -> LDS [pixel][channel] bf16 ---
  #define ES 66
  {
    float bias[2];
    #pragma unroll
    for (int nt = 0; nt < 2; ++nt) bias[nt] = mb_b[(ce * 2 + nt) * 16 + n15];
    #pragma unroll
    for (int i = 0; i < 4; ++i) {
      int mt = pg * 4 + i;
      int pbase = (mt >> 1) * 32 + (mt & 1) * 16;
      #pragma unroll
      for (int nt = 0; nt < 2; ++nt)
        #pragma unroll
        for (int reg = 0; reg < 4; ++reg) {
          float vv = fmaxf(acc[i][nt][reg] + bias[nt], 0.f);
          smem[(pbase + kq * 4 + reg) * ES + (ce * 2 + nt) * 16 + n15] = f2bf(vv);
        }
    }
  }
  __syncthreads();

  // dynamic heads: thread (p, half) handles pixel p, channels [half*32, half*32+32)
  int p = tid & 255, hh = tid >> 8;
  int ob = hh * 32;
  float mres[4] = {0.f, 0.f, 0.f, 0.f};
  float rres[4] = {0.f, 0.f, 0.f, 0.f};
  #pragma unroll 8
  for (int o = 0; o < 32; ++o) {
    float v = b2f(smem[p * ES + ob + o]);
    #pragma unroll
    for (int i = 0; i < 4; ++i) {
      mres[i] += ws_gp[i * NP + ob + o] * v;
      rres[i] += ws_gp[i * NP + 67 + ob + o] * v;
    }
  }
  float* pf = (float*)smem + 8704;   // byte 34816, past ES table (33792 B)
  if (hh) {
    #pragma unroll
    for (int i = 0; i < 4; ++i) { pf[p * 8 + i] = mres[i]; pf[p * 8 + 4 + i] = rres[i]; }
  }
  __syncthreads();
  if (!hh) {
    int r = p >> 5, xcol = p & 31;
    int gy = gy0 + r, gx = gx0 + xcol;
    float xc = -1.f + (2.f / 479.f) * (float)gx;
    float yc = -1.f + (2.f / 271.f) * (float)gy;
    int pix = gy * MW + gx;
    #pragma unroll
    for (int i = 0; i < 4; ++i) {
      const float* gp = ws_gp + i * NP;
      d_out[MASK_OFF + i * MN + pix] = mres[i] + pf[p * 8 + i]     + gp[66]  + gp[64]  * xc + gp[65]  * yc;
      d_out[REG_OFF  + i * MN + pix] = rres[i] + pf[p * 8 + 4 + i] + gp[133] + gp[131] * xc + gp[132] * yc;
    }
  }
}

// ------------------------------------------------------------------
// K5: feat_range MLP. Block = (i, 8 w-cols), 64 threads (thread = k).
// masks0 tile staged in LDS; inner loop reads are LDS broadcasts.
// ------------------------------------------------------------------
__global__ void k_mlp(const float* __restrict__ masks0, const float* __restrict__ w1,
                      const float* __restrict__ b1, const float* __restrict__ w2,
                      const float* __restrict__ b2, float* __restrict__ d_out) {
  __shared__ float mt[MH][8];        // 8704 B
  int blk = blockIdx.x;              // i*60 + wg
  int i  = blk / 60;
  int wg = blk - i * 60;
  int w0 = wg * 8;
  int k  = threadIdx.x;              // 0..63
  const float* mbase = masks0 + i * MN + w0;
  #pragma unroll 4
  for (int it = 0; it < 34; ++it) {
    int idx = it * 64 + k;           // 0..2175
    int h = idx >> 3, wj = idx & 7;
    mt[h][wj] = mbase[h * MW + wj];
  }
  __syncthreads();
  float s[8];
  #pragma unroll
  for (int wj = 0; wj < 8; ++wj) s[wj] = b1[k];
  #pragma unroll 4
  for (int h = 0; h < MH; ++h) {
    float wk = w1[h * HID + k];
    #pragma unroll
    for (int wj = 0; wj < 8; ++wj) s[wj] += mt[h][wj] * wk;
  }
  float w20 = w2[k * 2 + 0], w21 = w2[k * 2 + 1];
  #pragma unroll
  for (int wj = 0; wj < 8; ++wj) {
    float h1 = fmaxf(s[wj], 0.f);
    float o0 = h1 * w20;
    float o1 = h1 * w21;
    #pragma unroll
    for (int off = 32; off >= 1; off >>= 1) {
      o0 += __shfl_down(o0, off);
      o1 += __shfl_down(o1, off);
    }
    if (k == 0) {
      d_out[FEAT_OFF + (i * MW + w0 + wj) * 2 + 0] = o0 + b2[0];
      d_out[FEAT_OFF + (i * MW + w0 + wj) * 2 + 1] = o1 + b2[1];
    }
  }
}

// ------------------------------------------------------------------
extern "C" void kernel_launch(void* const* d_in, const int* in_sizes, int n_in,
                              void* d_out, int out_size, void* d_ws, size_t ws_size,
                              hipStream_t stream) {
  const float* out0     = (const float*)d_in[0];
  const float* out1     = (const float*)d_in[1];
  const float* hm_w     = (const float*)d_in[2];
  const float* hm_b     = (const float*)d_in[3];
  const float* params_w = (const float*)d_in[4];
  const float* params_b = (const float*)d_in[5];
  const float* mb_w     = (const float*)d_in[6];
  const float* mb_b     = (const float*)d_in[7];
  const float* mlp_w1   = (const float*)d_in[8];
  const float* mlp_b1   = (const float*)d_in[9];
  const float* mlp_w2   = (const float*)d_in[10];
  const float* mlp_b2   = (const float*)d_in[11];

  float* ws      = (float*)d_ws;
  float* ws_hm   = ws + WS_HM;
  float* candv   = ws + WS_CV;
  int*   candi   = (int*)(ws + WS_CI);
  float* ws_gp   = ws + WS_GP;
  unsigned short* ws_wt = (unsigned short*)(ws + WS_WT_F);
  float* out     = (float*)d_out;

  k_prep<<<1086, 256, 0, stream>>>(mb_w, ws_wt, out1, hm_w, hm_b, ws_hm);
  k_nms_top<<<128, 256, 0, stream>>>(ws_hm, candv, candi);
  k_gen<<<NI, 256, 0, stream>>>(candv, candi, out1, params_w, params_b, ws_gp, out);
  dim3 gconv(MW / 32, MH / 8);   // 15 x 34
  k_conv_mfma<<<gconv, 512, 0, stream>>>(out0, ws_wt, mb_b, ws_gp, out);
  k_mlp<<<NI * 60, 64, 0, stream>>>(out + MASK_OFF, mlp_w1, mlp_b1, mlp_w2, mlp_b2, out);
}

// Round 3
// 328.071 us; speedup vs baseline: 1.1688x; 1.1688x over previous
//
#include <hip/hip_runtime.h>
#include <math.h>
#include <limits.h>

// ---- problem constants ----
#define C_IN 256
#define HM_H 136
#define HM_W 240
#define HM_N (HM_H * HM_W)      // 32640
#define MB   64
#define MH   272
#define MW   480
#define MN   (MH * MW)          // 130560
#define NP   134
#define NI   4
#define HID  64

// d_out layout (floats): scores[4] | inds[4] | regs0[4*MN] | masks0[4*MN] | feat[4*480*2]
#define REG_OFF   8
#define MASK_OFF  (8 + NI * MN)
#define FEAT_OFF  (8 + 2 * NI * MN)

// ws layout (floats): hm[32640] | cand_v[512]+cand_i[512] | gp[536] | wt @ 65824
#define WS_HM   0
#define WS_CV   HM_N
#define WS_CI   (HM_N + 512)
#define WS_GP   (2 * HM_N)
#define WS_WT_F 65824

typedef float  f32x4  __attribute__((ext_vector_type(4)));
typedef short  bf16x8 __attribute__((ext_vector_type(8)));
typedef unsigned short u16x8 __attribute__((ext_vector_type(8)));

__device__ __forceinline__ unsigned short f2bf(float f) {
  unsigned int u = __float_as_uint(f);
  u += 0x7FFFu + ((u >> 16) & 1u);
  return (unsigned short)(u >> 16);
}
__device__ __forceinline__ float b2f(unsigned short h) {
  return __uint_as_float(((unsigned int)h) << 16);
}

__device__ __forceinline__ void glds16(const void* g, void* l) {
  __builtin_amdgcn_global_load_lds(
      (const __attribute__((address_space(1))) unsigned int*)g,
      (__attribute__((address_space(3))) unsigned int*)l, 16, 0, 0);
}

// ------------------------------------------------------------------
// K0: merged weight-prep + heatmap.
// ------------------------------------------------------------------
__global__ void k_prep(const float* __restrict__ mb_w, unsigned short* __restrict__ wt,
                       const float* __restrict__ out1, const float* __restrict__ hm_w,
                       const float* __restrict__ hm_b, float* __restrict__ ws_hm) {
  __shared__ float part[4][64];
  if (blockIdx.x < 576) {
    int idx = blockIdx.x * 256 + threadIdx.x;     // 147456 total
    int j    = idx & 7;
    int lane = (idx >> 3) & 63;
    int nt   = (idx >> 9) & 3;
    int gt   = idx >> 11;
    int t    = gt % 9;
    int g    = gt / 9;
    int n = nt * 16 + (lane & 15);
    int c = g * 32 + (lane >> 4) * 8 + j;
    wt[idx] = f2bf(mb_w[(n * C_IN + c) * 9 + t]);
  } else {
    int b = blockIdx.x - 576, t = threadIdx.x;
    int cg = t >> 6, pl = t & 63;
    int p = b * 64 + pl;                         // 510*64 = 32640
    float s = 0.f;
    #pragma unroll 16
    for (int c = 0; c < 64; ++c)
      s += hm_w[cg * 64 + c] * out1[(cg * 64 + c) * HM_N + p];
    part[cg][pl] = s;
    __syncthreads();
    if (t < 64) {
      float tot = part[0][t] + part[1][t] + part[2][t] + part[3][t] + hm_b[0];
      float sig = 1.f / (1.f + expf(-tot));
      sig = fminf(fmaxf(sig, 1e-4f), 1.f - 1e-4f);
      ws_hm[b * 64 + t] = sig;
    }
  }
}

// ------------------------------------------------------------------
// top-4 list merge helpers
// ------------------------------------------------------------------
__device__ __forceinline__ bool better(float av, int ai, float bv, int bi) {
  return (av > bv) || (av == bv && ai < bi);
}

template<int NTHR>
__device__ void top4_tree(float* sv, int* si, int t) {
  for (int s = NTHR / 2; s >= 1; s >>= 1) {
    if (t < s) {
      float a[4], b[4]; int ai[4], bj[4];
      #pragma unroll
      for (int k = 0; k < 4; ++k) {
        a[k] = sv[t * 4 + k];        ai[k] = si[t * 4 + k];
        b[k] = sv[(t + s) * 4 + k];  bj[k] = si[(t + s) * 4 + k];
      }
      float ov[4]; int oi[4];
      int i = 0, j = 0;
      #pragma unroll
      for (int k = 0; k < 4; ++k) {
        if (better(a[i], ai[i], b[j], bj[j])) { ov[k] = a[i]; oi[k] = ai[i]; ++i; }
        else                                   { ov[k] = b[j]; oi[k] = bj[j]; ++j; }
      }
      #pragma unroll
      for (int k = 0; k < 4; ++k) { sv[t * 4 + k] = ov[k]; si[t * 4 + k] = oi[k]; }
    }
    __syncthreads();
  }
}

// ------------------------------------------------------------------
// K2a: fused NMS + per-block top-4 (128 blocks x 255 pixels)
// ------------------------------------------------------------------
__global__ void k_nms_top(const float* __restrict__ ws_hm, float* __restrict__ candv,
                          int* __restrict__ candi) {
  __shared__ float sv[256 * 4];
  __shared__ int   si[256 * 4];
  int b = blockIdx.x, t = threadIdx.x;
  float v = -1.f; int idx = INT_MAX;
  if (t < 255) {
    int p = b * 255 + t;
    int y = p / HM_W, x = p - y * HM_W;
    float c = ws_hm[p], m = c;
    #pragma unroll
    for (int dy = -1; dy <= 1; ++dy)
      #pragma unroll
      for (int dx = -1; dx <= 1; ++dx) {
        int yy = y + dy, xx = x + dx;
        if (yy >= 0 && yy < HM_H && xx >= 0 && xx < HM_W)
          m = fmaxf(m, ws_hm[yy * HM_W + xx]);
      }
    v = (c == m) ? c : 0.f;
    idx = p;
  }
  sv[t * 4] = v; si[t * 4] = idx;
  #pragma unroll
  for (int k = 1; k < 4; ++k) { sv[t * 4 + k] = -1.f; si[t * 4 + k] = INT_MAX; }
  __syncthreads();
  top4_tree<256>(sv, si, t);
  if (t == 0) {
    #pragma unroll
    for (int k = 0; k < 4; ++k) { candv[b * 4 + k] = sv[k]; candi[b * 4 + k] = si[k]; }
  }
}

// ------------------------------------------------------------------
// K3: redundant final top-k merge + gen_params. Block i -> instance i.
// ------------------------------------------------------------------
__global__ void k_gen(const float* __restrict__ candv, const int* __restrict__ candi,
                      const float* __restrict__ out1, const float* __restrict__ params_w,
                      const float* __restrict__ params_b, float* __restrict__ ws_gp,
                      float* __restrict__ d_out) {
  __shared__ float sv[128 * 4];
  __shared__ int   si[128 * 4];
  __shared__ float col[C_IN];
  int t = threadIdx.x, i = blockIdx.x;
  if (t < 128) {
    #pragma unroll
    for (int k = 0; k < 4; ++k) { sv[t * 4 + k] = candv[t * 4 + k]; si[t * 4 + k] = candi[t * 4 + k]; }
  }
  __syncthreads();
  top4_tree<128>(sv, si, t);
  if (i == 0 && t < 4) {
    d_out[t]     = sv[t];
    d_out[4 + t] = (float)si[t];
  }
  int p = si[i];
  col[t] = out1[t * HM_N + p];
  __syncthreads();
  if (t < NP) {
    float s = params_b[t];
    #pragma unroll 8
    for (int c = 0; c < C_IN; ++c) s += params_w[t * C_IN + c] * col[c];
    ws_gp[i * NP + t] = s;
  }
}

// ------------------------------------------------------------------
// K4 v4: producer-specialized MFMA implicit-GEMM conv.
//  - waves 0-6: HBM A-staging (reg-staged, stored 1 full iter after issue;
//    their vmcnt stream contains ONLY A loads -> no FIFO coupling)
//  - wave 7: weight staging via global_load_lds into LDS (vmcnt stream
//    contains ONLY L2-fast W loads; vmcnt(0) per phase is cheap)
//  - all 8 waves compute; B-fragments read from LDS (lgkmcnt)
//  - 3 phases/iter, raw barriers (lgkmcnt(0)+s_barrier, NO vmcnt drain):
//    A loads stay in flight across barriers for a full iteration.
// LDS: A 2x23040B + W 2x12288B = 70656B -> 2 blocks/CU.
// ------------------------------------------------------------------
#define RP   36                 // stored x positions per row (gx0-1 .. gx0+34)
#define BUFU (10 * RP * 32)     // 11520 ushorts = 23040 B per A buffer
#define WOFF (2 * BUFU)         // W region starts at ushort 23040 (byte 46080)

#define PIPE_BARRIER() do {                                   \
    __builtin_amdgcn_sched_barrier(0);                        \
    asm volatile("s_waitcnt lgkmcnt(0)" ::: "memory");        \
    __builtin_amdgcn_s_barrier();                             \
    __builtin_amdgcn_sched_barrier(0);                        \
  } while (0)

// stage weight group G (3 taps = 12288B) into W buf (G&1); wave 7 only
#define STAGE_W(G)                                                        \
  if (wv == 7 && (G) < 24) {                                              \
    const char* wsrc = (const char*)wt + (G) * 12288 + lane * 16;         \
    char* wdst = (char*)smem + 46080 + ((G) & 1) * 12288;                 \
    _Pragma("unroll")                                                     \
    for (int i_ = 0; i_ < 12; ++i_)                                       \
      glds16(wsrc + i_ * 1024, wdst + i_ * 1024);                         \
  }

#define TAPS3(P) {                                                        \
    const unsigned short* wl = smem + WOFF + (((g + (P)) & 1) * 6144)     \
                               + ce * 1024 + lane * 8;                    \
    _Pragma("unroll")                                                     \
    for (int tt = 0; tt < 3; ++tt) {                                      \
      bf16x8 bb0 = *(const bf16x8*)(wl + tt * 2048);                      \
      bf16x8 bb1 = *(const bf16x8*)(wl + tt * 2048 + 512);                \
      unsigned pk = lrdp[(P) * 3 + tt];                                   \
      const unsigned short* c0 = cur + (pk & 0xFFFFu);                    \
      const unsigned short* c1 = cur + (pk >> 16);                        \
      bf16x8 a0 = *(const bf16x8*)c0;                                     \
      bf16x8 a1 = *(const bf16x8*)(c0 + 512);                             \
      bf16x8 a2 = *(const bf16x8*)c1;                                     \
      bf16x8 a3 = *(const bf16x8*)(c1 + 512);                             \
      acc[0][0] = __builtin_amdgcn_mfma_f32_16x16x32_bf16(a0, bb0, acc[0][0], 0, 0, 0); \
      acc[0][1] = __builtin_amdgcn_mfma_f32_16x16x32_bf16(a0, bb1, acc[0][1], 0, 0, 0); \
      acc[1][0] = __builtin_amdgcn_mfma_f32_16x16x32_bf16(a1, bb0, acc[1][0], 0, 0, 0); \
      acc[1][1] = __builtin_amdgcn_mfma_f32_16x16x32_bf16(a1, bb1, acc[1][1], 0, 0, 0); \
      acc[2][0] = __builtin_amdgcn_mfma_f32_16x16x32_bf16(a2, bb0, acc[2][0], 0, 0, 0); \
      acc[2][1] = __builtin_amdgcn_mfma_f32_16x16x32_bf16(a2, bb1, acc[2][1], 0, 0, 0); \
      acc[3][0] = __builtin_amdgcn_mfma_f32_16x16x32_bf16(a3, bb0, acc[3][0], 0, 0, 0); \
      acc[3][1] = __builtin_amdgcn_mfma_f32_16x16x32_bf16(a3, bb1, acc[3][1], 0, 0, 0); \
    } }

__device__ __forceinline__ void stage_store8(unsigned short* buf, const f32x4* dq,
                                             bool gv, const int* lw, unsigned sm) {
  #pragma unroll
  for (int e = 0; e < 4; ++e) if ((sm >> e) & 1u) {
    u16x8 v;
    #pragma unroll
    for (int j = 0; j < 8; ++j) v[j] = f2bf(gv ? dq[j][e] : 0.f);
    *(u16x8*)(buf + lw[e]) = v;
  }
}

__global__ __launch_bounds__(512, 3) void k_conv_mfma(
    const float* __restrict__ out0, const unsigned short* __restrict__ wt,
    const float* __restrict__ mb_b, const float* __restrict__ ws_gp,
    float* __restrict__ d_out) {
  __shared__ unsigned short smem[2 * BUFU + 2 * 6144];   // 70656 B

  int tid  = threadIdx.x;
  int lane = tid & 63;
  int wv   = tid >> 6;       // wave 0..7
  int n15  = lane & 15;
  int kq   = lane >> 4;
  int pg   = wv & 3;         // pixel group (64 px)
  int ce   = wv >> 2;        // channel half (32 out-ch)
  int gx0 = blockIdx.x * 32, gy0 = blockIdx.y * 8;

  // --- A staging descriptor: 400 units of (co8, row, qx); unit = 8 float4 -> 4 b128 ---
  bool act = tid < 400;      // all within waves 0..6
  int u    = act ? tid : 0;
  int co8  = u / 100;                 // 0..3  (8-channel group)
  int rem  = u - co8 * 100;
  int row  = rem / 10;                // 0..9  (stored row)
  int qx   = rem - row * 10;          // 0..9  (x quad)
  int iy   = gy0 + row - 1;
  int ixq  = gx0 + 4 * qx - 4;        // 16B-aligned quad
  bool gvld = act && (iy >= 0) && (iy < MH) && (ixq >= 0) && (ixq + 3 < MW);
  int goff  = gvld ? (co8 * 8 * MN + iy * MW + ixq) : 0;
  int lws[4]; unsigned smask = 0;
  #pragma unroll
  for (int e = 0; e < 4; ++e) {
    int sx = 4 * qx - 3 + e;          // stored x index
    bool sv = act && (sx >= 0) && (sx < RP);
    int pixw = row * RP + (sv ? sx : 0);
    int w2 = (pixw ^ (pixw >> 2)) & 3;
    int q  = (pixw ^ row) & 1;
    lws[e] = (pixw >> 1) * 64 + ((co8 ^ w2) << 4) + q * 8;
    if (sv) smask |= (1u << e);
  }

  // --- A-frag LDS read offsets: packed (d0 | d1<<16) per tap; +512 = x-half ---
  unsigned lrdp[9];
  #pragma unroll
  for (int t = 0; t < 9; ++t) {
    int ty = t / 3, tx = t - ty * 3;
    int sr0 = pg * 2 + ty;            // stored row for subtiles i=0,1
    int pix0 = sr0 * RP + n15 + tx;
    int w20 = (pix0 ^ (pix0 >> 2)) & 3;
    int q0  = (pix0 ^ sr0) & 1;
    unsigned o0 = (pix0 >> 1) * 64 + ((kq ^ w20) << 4) + q0 * 8;
    int sr1 = sr0 + 1;                // subtiles i=2,3
    int pix1 = sr1 * RP + n15 + tx;
    int w21 = (pix1 ^ (pix1 >> 2)) & 3;
    int q1  = (pix1 ^ sr1) & 1;
    unsigned o1 = (pix1 >> 1) * 64 + ((kq ^ w21) << 4) + q1 * 8;
    lrdp[t] = o0 | (o1 << 16);
  }

  bool aload = (tid < 448);           // waves 0..6 issue A loads (exec-masked to act)

  // --- prologue: stage A tile0 -> buf0; issue L(1); stage W group0 ---
  f32x4 dq[8];
  if (act) {
    const float* sp = out0 + goff;
    #pragma unroll
    for (int j = 0; j < 8; ++j) dq[j] = *(const f32x4*)(sp + j * MN);
  }
  stage_store8(smem, dq, gvld, lws, smask);          // waits only tile0 loads
  __builtin_amdgcn_sched_barrier(0);
  if (act) {
    const float* sp = out0 + 32 * MN + goff;         // L(1)
    #pragma unroll
    for (int j = 0; j < 8; ++j) dq[j] = *(const f32x4*)(sp + j * MN);
  }
  STAGE_W(0);
  if (wv == 7) asm volatile("s_waitcnt vmcnt(0)" ::: "memory");
  PIPE_BARRIER();

  f32x4 acc[4][2];
  #pragma unroll
  for (int i = 0; i < 4; ++i)
    #pragma unroll
    for (int nt = 0; nt < 2; ++nt)
      acc[i][nt] = (f32x4){0.f, 0.f, 0.f, 0.f};

  #pragma unroll 1
  for (int g = 0; g < 8; ++g) {
    const unsigned short* cur = smem + (g & 1) * BUFU;
    unsigned short*       nxt = smem + ((g + 1) & 1) * BUFU;

    // ---- phase 0: A store(L(g+1)) + A issue(L(g+2)) | W grp(3g+1) | taps 0-2
    STAGE_W(3 * g + 1);
    if (g <= 6) stage_store8(nxt, dq, gvld, lws, smask);   // waits L(g+1): 1 iter old
    __builtin_amdgcn_sched_barrier(0);
    if (g <= 5 && act) {
      const float* sp = out0 + (g + 2) * (32 * MN) + goff;
      #pragma unroll
      for (int j = 0; j < 8; ++j) dq[j] = *(const f32x4*)(sp + j * MN);
    }
    __builtin_amdgcn_sched_barrier(0);
    TAPS3(0)
    if (wv == 7) asm volatile("s_waitcnt vmcnt(0)" ::: "memory");
    PIPE_BARRIER();

    // ---- phase 1: W grp(3g+2) | taps 3-5
    STAGE_W(3 * g + 2);
    TAPS3(1)
    if (wv == 7) asm volatile("s_waitcnt vmcnt(0)" ::: "memory");
    PIPE_BARRIER();

    // ---- phase 2: W grp(3g+3) | taps 6-8
    STAGE_W(3 * g + 3);
    TAPS3(2)
    if (wv == 7) asm volatile("s_waitcnt vmcnt(0)" ::: "memory");
    PIPE_BARRIER();
  }

  // --- epilogue: bias+relu, acc -> LDS [pixel][channel] bf16 ---
  #define ES 66
  {
    float bias[2];
    #pragma unroll
    for (int nt = 0; nt < 2; ++nt) bias[nt] = mb_b[(ce * 2 + nt) * 16 + n15];
    #pragma unroll
    for (int i = 0; i < 4; ++i) {
      int mt = pg * 4 + i;
      int pbase = (mt >> 1) * 32 + (mt & 1) * 16;
      #pragma unroll
      for (int nt = 0; nt < 2; ++nt)
        #pragma unroll
        for (int reg = 0; reg < 4; ++reg) {
          float vv = fmaxf(acc[i][nt][reg] + bias[nt], 0.f);
          smem[(pbase + kq * 4 + reg) * ES + (ce * 2 + nt) * 16 + n15] = f2bf(vv);
        }
    }
  }
  __syncthreads();

  // dynamic heads: thread (p, half) handles pixel p, channels [half*32, half*32+32)
  int p = tid & 255, hh = tid >> 8;
  int ob = hh * 32;
  float mres[4] = {0.f, 0.f, 0.f, 0.f};
  float rres[4] = {0.f, 0.f, 0.f, 0.f};
  #pragma unroll 8
  for (int o = 0; o < 32; ++o) {
    float v = b2f(smem[p * ES + ob + o]);
    #pragma unroll
    for (int i = 0; i < 4; ++i) {
      mres[i] += ws_gp[i * NP + ob + o] * v;
      rres[i] += ws_gp[i * NP + 67 + ob + o] * v;
    }
  }
  float* pf = (float*)smem + 8704;   // byte 34816, past ES table (33792 B)
  if (hh) {
    #pragma unroll
    for (int i = 0; i < 4; ++i) { pf[p * 8 + i] = mres[i]; pf[p * 8 + 4 + i] = rres[i]; }
  }
  __syncthreads();
  if (!hh) {
    int r = p >> 5, xcol = p & 31;
    int gy = gy0 + r, gx = gx0 + xcol;
    float xc = -1.f + (2.f / 479.f) * (float)gx;
    float yc = -1.f + (2.f / 271.f) * (float)gy;
    int pix = gy * MW + gx;
    #pragma unroll
    for (int i = 0; i < 4; ++i) {
      const float* gp = ws_gp + i * NP;
      d_out[MASK_OFF + i * MN + pix] = mres[i] + pf[p * 8 + i]     + gp[66]  + gp[64]  * xc + gp[65]  * yc;
      d_out[REG_OFF  + i * MN + pix] = rres[i] + pf[p * 8 + 4 + i] + gp[133] + gp[131] * xc + gp[132] * yc;
    }
  }
  (void)aload;
}

// ------------------------------------------------------------------
// K5: feat_range MLP (R1 form: 1920 blocks x 64 threads)
// ------------------------------------------------------------------
__global__ void k_mlp(const float* __restrict__ masks0, const float* __restrict__ w1,
                      const float* __restrict__ b1, const float* __restrict__ w2,
                      const float* __restrict__ b2, float* __restrict__ d_out) {
  int blk = blockIdx.x;          // i*480 + w
  int i = blk / MW;
  int w = blk - i * MW;
  int k = threadIdx.x;           // 0..63
  const float* mcol = masks0 + i * MN + w;
  float s = b1[k];
  #pragma unroll 4
  for (int h = 0; h < MH; ++h) s += mcol[h * MW] * w1[h * HID + k];
  s = fmaxf(s, 0.f);
  float o0 = s * w2[k * 2 + 0];
  float o1 = s * w2[k * 2 + 1];
  #pragma unroll
  for (int off = 32; off >= 1; off >>= 1) {
    o0 += __shfl_down(o0, off);
    o1 += __shfl_down(o1, off);
  }
  if (k == 0) {
    d_out[FEAT_OFF + blk * 2 + 0] = o0 + b2[0];
    d_out[FEAT_OFF + blk * 2 + 1] = o1 + b2[1];
  }
}

// ------------------------------------------------------------------
extern "C" void kernel_launch(void* const* d_in, const int* in_sizes, int n_in,
                              void* d_out, int out_size, void* d_ws, size_t ws_size,
                              hipStream_t stream) {
  const float* out0     = (const float*)d_in[0];
  const float* out1     = (const float*)d_in[1];
  const float* hm_w     = (const float*)d_in[2];
  const float* hm_b     = (const float*)d_in[3];
  const float* params_w = (const float*)d_in[4];
  const float* params_b = (const float*)d_in[5];
  const float* mb_w     = (const float*)d_in[6];
  const float* mb_b     = (const float*)d_in[7];
  const float* mlp_w1   = (const float*)d_in[8];
  const float* mlp_b1   = (const float*)d_in[9];
  const float* mlp_w2   = (const float*)d_in[10];
  const float* mlp_b2   = (const float*)d_in[11];

  float* ws      = (float*)d_ws;
  float* ws_hm   = ws + WS_HM;
  float* candv   = ws + WS_CV;
  int*   candi   = (int*)(ws + WS_CI);
  float* ws_gp   = ws + WS_GP;
  unsigned short* ws_wt = (unsigned short*)(ws + WS_WT_F);
  float* out     = (float*)d_out;

  k_prep<<<1086, 256, 0, stream>>>(mb_w, ws_wt, out1, hm_w, hm_b, ws_hm);
  k_nms_top<<<128, 256, 0, stream>>>(ws_hm, candv, candi);
  k_gen<<<NI, 256, 0, stream>>>(candv, candi, out1, params_w, params_b, ws_gp, out);
  dim3 gconv(MW / 32, MH / 8);   // 15 x 34
  k_conv_mfma<<<gconv, 512, 0, stream>>>(out0, ws_wt, mb_b, ws_gp, out);
  k_mlp<<<NI * MW, 64, 0, stream>>>(out + MASK_OFF, mlp_w1, mlp_b1, mlp_w2, mlp_b2, out);
}

// Round 4
// 311.562 us; speedup vs baseline: 1.2308x; 1.0530x over previous
//
#include <hip/hip_runtime.h>
#include <math.h>
#include <limits.h>

// ---- problem constants ----
#define C_IN 256
#define HM_H 136
#define HM_W 240
#define HM_N (HM_H * HM_W)      // 32640
#define MB   64
#define MH   272
#define MW   480
#define MN   (MH * MW)          // 130560
#define NP   134
#define NI   4
#define HID  64

// d_out layout (floats): scores[4] | inds[4] | regs0[4*MN] | masks0[4*MN] | feat[4*480*2]
#define REG_OFF   8
#define MASK_OFF  (8 + NI * MN)
#define FEAT_OFF  (8 + 2 * NI * MN)

// ws layout (floats): hm[32640] | cand_v[512]+cand_i[512] | gp[536] | wt @ 65824
#define WS_HM   0
#define WS_CV   HM_N
#define WS_CI   (HM_N + 512)
#define WS_GP   (2 * HM_N)
#define WS_WT_F 65824

typedef float  f32x4  __attribute__((ext_vector_type(4)));
typedef short  bf16x8 __attribute__((ext_vector_type(8)));
typedef unsigned short u16x8 __attribute__((ext_vector_type(8)));

__device__ __forceinline__ unsigned short f2bf(float f) {
  unsigned int u = __float_as_uint(f);
  u += 0x7FFFu + ((u >> 16) & 1u);
  return (unsigned short)(u >> 16);
}
__device__ __forceinline__ float b2f(unsigned short h) {
  return __uint_as_float(((unsigned int)h) << 16);
}

__device__ __forceinline__ void glds16(const void* g, void* l) {
  __builtin_amdgcn_global_load_lds(
      (const __attribute__((address_space(1))) unsigned int*)g,
      (__attribute__((address_space(3))) unsigned int*)l, 16, 0, 0);
}

// ------------------------------------------------------------------
// K0: merged weight-prep + heatmap.
// ------------------------------------------------------------------
__global__ void k_prep(const float* __restrict__ mb_w, unsigned short* __restrict__ wt,
                       const float* __restrict__ out1, const float* __restrict__ hm_w,
                       const float* __restrict__ hm_b, float* __restrict__ ws_hm) {
  __shared__ float part[4][64];
  if (blockIdx.x < 576) {
    int idx = blockIdx.x * 256 + threadIdx.x;     // 147456 total
    int j    = idx & 7;
    int lane = (idx >> 3) & 63;
    int nt   = (idx >> 9) & 3;
    int gt   = idx >> 11;
    int t    = gt % 9;
    int g    = gt / 9;
    int n = nt * 16 + (lane & 15);
    int c = g * 32 + (lane >> 4) * 8 + j;
    wt[idx] = f2bf(mb_w[(n * C_IN + c) * 9 + t]);
  } else {
    int b = blockIdx.x - 576, t = threadIdx.x;
    int cg = t >> 6, pl = t & 63;
    int p = b * 64 + pl;                         // 510*64 = 32640
    float s = 0.f;
    #pragma unroll 16
    for (int c = 0; c < 64; ++c)
      s += hm_w[cg * 64 + c] * out1[(cg * 64 + c) * HM_N + p];
    part[cg][pl] = s;
    __syncthreads();
    if (t < 64) {
      float tot = part[0][t] + part[1][t] + part[2][t] + part[3][t] + hm_b[0];
      float sig = 1.f / (1.f + expf(-tot));
      sig = fminf(fmaxf(sig, 1e-4f), 1.f - 1e-4f);
      ws_hm[b * 64 + t] = sig;
    }
  }
}

// ------------------------------------------------------------------
// top-4 list merge helpers
// ------------------------------------------------------------------
__device__ __forceinline__ bool better(float av, int ai, float bv, int bi) {
  return (av > bv) || (av == bv && ai < bi);
}

template<int NTHR>
__device__ void top4_tree(float* sv, int* si, int t) {
  for (int s = NTHR / 2; s >= 1; s >>= 1) {
    if (t < s) {
      float a[4], b[4]; int ai[4], bj[4];
      #pragma unroll
      for (int k = 0; k < 4; ++k) {
        a[k] = sv[t * 4 + k];        ai[k] = si[t * 4 + k];
        b[k] = sv[(t + s) * 4 + k];  bj[k] = si[(t + s) * 4 + k];
      }
      float ov[4]; int oi[4];
      int i = 0, j = 0;
      #pragma unroll
      for (int k = 0; k < 4; ++k) {
        if (better(a[i], ai[i], b[j], bj[j])) { ov[k] = a[i]; oi[k] = ai[i]; ++i; }
        else                                   { ov[k] = b[j]; oi[k] = bj[j]; ++j; }
      }
      #pragma unroll
      for (int k = 0; k < 4; ++k) { sv[t * 4 + k] = ov[k]; si[t * 4 + k] = oi[k]; }
    }
    __syncthreads();
  }
}

// ------------------------------------------------------------------
// K2a: fused NMS + per-block top-4 (128 blocks x 255 pixels)
// ------------------------------------------------------------------
__global__ void k_nms_top(const float* __restrict__ ws_hm, float* __restrict__ candv,
                          int* __restrict__ candi) {
  __shared__ float sv[256 * 4];
  __shared__ int   si[256 * 4];
  int b = blockIdx.x, t = threadIdx.x;
  float v = -1.f; int idx = INT_MAX;
  if (t < 255) {
    int p = b * 255 + t;
    int y = p / HM_W, x = p - y * HM_W;
    float c = ws_hm[p], m = c;
    #pragma unroll
    for (int dy = -1; dy <= 1; ++dy)
      #pragma unroll
      for (int dx = -1; dx <= 1; ++dx) {
        int yy = y + dy, xx = x + dx;
        if (yy >= 0 && yy < HM_H && xx >= 0 && xx < HM_W)
          m = fmaxf(m, ws_hm[yy * HM_W + xx]);
      }
    v = (c == m) ? c : 0.f;
    idx = p;
  }
  sv[t * 4] = v; si[t * 4] = idx;
  #pragma unroll
  for (int k = 1; k < 4; ++k) { sv[t * 4 + k] = -1.f; si[t * 4 + k] = INT_MAX; }
  __syncthreads();
  top4_tree<256>(sv, si, t);
  if (t == 0) {
    #pragma unroll
    for (int k = 0; k < 4; ++k) { candv[b * 4 + k] = sv[k]; candi[b * 4 + k] = si[k]; }
  }
}

// ------------------------------------------------------------------
// K3: redundant final top-k merge + gen_params. Block i -> instance i.
// ------------------------------------------------------------------
__global__ void k_gen(const float* __restrict__ candv, const int* __restrict__ candi,
                      const float* __restrict__ out1, const float* __restrict__ params_w,
                      const float* __restrict__ params_b, float* __restrict__ ws_gp,
                      float* __restrict__ d_out) {
  __shared__ float sv[128 * 4];
  __shared__ int   si[128 * 4];
  __shared__ float col[C_IN];
  int t = threadIdx.x, i = blockIdx.x;
  if (t < 128) {
    #pragma unroll
    for (int k = 0; k < 4; ++k) { sv[t * 4 + k] = candv[t * 4 + k]; si[t * 4 + k] = candi[t * 4 + k]; }
  }
  __syncthreads();
  top4_tree<128>(sv, si, t);
  if (i == 0 && t < 4) {
    d_out[t]     = sv[t];
    d_out[4 + t] = (float)si[t];
  }
  int p = si[i];
  col[t] = out1[t * HM_N + p];
  __syncthreads();
  if (t < NP) {
    float s = params_b[t];
    #pragma unroll 8
    for (int c = 0; c < C_IN; ++c) s += params_w[t * C_IN + c] * col[c];
    ws_gp[i * NP + t] = s;
  }
}

// ------------------------------------------------------------------
// K4 v5: wave = 64px x 64ch (acc[4][4], 32 FLOP/LDS-byte), block 16x32 px.
//  - waves 0-5(.6): A-staging in 2 sub-stages (issue phase k, store k+1)
//  - wave 7: W staging 2 phases ahead, 3 LDS bufs, counted vmcnt(12)
//  - 3 phases/iter, raw barriers (lgkmcnt(0)+s_barrier, no vmcnt drain)
// LDS: A 2x41472B + W 3x12288B = 119808 B -> 1 block/CU.
// ------------------------------------------------------------------
#define SR   18                 // stored rows (16 + 2 halo)
#define RP   36                 // stored x positions per row (gx0-1 .. gx0+34)
#define BUFU (SR * RP * 32)     // 20736 ushorts = 41472 B per A buffer
#define WOFF (2 * BUFU)         // ushort idx 41472; W bufs: +b*6144 ushorts

#define PIPE_BARRIER() do {                                   \
    __builtin_amdgcn_sched_barrier(0);                        \
    asm volatile("s_waitcnt lgkmcnt(0)" ::: "memory");        \
    __builtin_amdgcn_s_barrier();                             \
    __builtin_amdgcn_sched_barrier(0);                        \
  } while (0)

// stage weight group G (3 taps = 12288B) into W buf B; wave 7 only
#define STAGE_W3(G, B)                                                    \
  if (wv == 7 && (G) < 24) {                                              \
    const char* wsrc = (const char*)wt + (G) * 12288 + lane * 16;         \
    char* wdst = (char*)smem + 2 * WOFF + (B) * 12288;                    \
    _Pragma("unroll")                                                     \
    for (int i_ = 0; i_ < 12; ++i_)                                       \
      glds16(wsrc + i_ * 1024, wdst + i_ * 1024);                         \
  }

#define MFMA16(A, B, C) __builtin_amdgcn_mfma_f32_16x16x32_bf16(A, B, C, 0, 0, 0)

#define TAPS3(P) {                                                        \
    const unsigned short* wl = smem + WOFF + (P) * 6144 + lane * 8;       \
    _Pragma("unroll")                                                     \
    for (int tt = 0; tt < 3; ++tt) {                                      \
      bf16x8 bb0 = *(const bf16x8*)(wl + tt * 2048);                      \
      bf16x8 bb1 = *(const bf16x8*)(wl + tt * 2048 + 512);                \
      bf16x8 bb2 = *(const bf16x8*)(wl + tt * 2048 + 1024);               \
      bf16x8 bb3 = *(const bf16x8*)(wl + tt * 2048 + 1536);               \
      unsigned pk = lrdp[(P) * 3 + tt];                                   \
      const unsigned short* c0 = cur + (pk & 0xFFFFu);                    \
      const unsigned short* c1 = cur + (pk >> 16);                        \
      bf16x8 a0 = *(const bf16x8*)c0;                                     \
      bf16x8 a1 = *(const bf16x8*)(c0 + 512);                             \
      bf16x8 a2 = *(const bf16x8*)c1;                                     \
      bf16x8 a3 = *(const bf16x8*)(c1 + 512);                             \
      acc[0][0] = MFMA16(a0, bb0, acc[0][0]);                             \
      acc[0][1] = MFMA16(a0, bb1, acc[0][1]);                             \
      acc[0][2] = MFMA16(a0, bb2, acc[0][2]);                             \
      acc[0][3] = MFMA16(a0, bb3, acc[0][3]);                             \
      acc[1][0] = MFMA16(a1, bb0, acc[1][0]);                             \
      acc[1][1] = MFMA16(a1, bb1, acc[1][1]);                             \
      acc[1][2] = MFMA16(a1, bb2, acc[1][2]);                             \
      acc[1][3] = MFMA16(a1, bb3, acc[1][3]);                             \
      acc[2][0] = MFMA16(a2, bb0, acc[2][0]);                             \
      acc[2][1] = MFMA16(a2, bb1, acc[2][1]);                             \
      acc[2][2] = MFMA16(a2, bb2, acc[2][2]);                             \
      acc[2][3] = MFMA16(a2, bb3, acc[2][3]);                             \
      acc[3][0] = MFMA16(a3, bb0, acc[3][0]);                             \
      acc[3][1] = MFMA16(a3, bb1, acc[3][1]);                             \
      acc[3][2] = MFMA16(a3, bb2, acc[3][2]);                             \
      acc[3][3] = MFMA16(a3, bb3, acc[3][3]);                             \
    } }

__device__ __forceinline__ void stage_store8(unsigned short* buf, const f32x4* dq,
                                             bool gv, const int* lw, unsigned sm) {
  #pragma unroll
  for (int e = 0; e < 4; ++e) if ((sm >> e) & 1u) {
    u16x8 v;
    #pragma unroll
    for (int j = 0; j < 8; ++j) v[j] = f2bf(gv ? dq[j][e] : 0.f);
    *(u16x8*)(buf + lw[e]) = v;
  }
}

__global__ __launch_bounds__(512, 2) void k_conv_mfma(
    const float* __restrict__ out0, const unsigned short* __restrict__ wt,
    const float* __restrict__ mb_b, const float* __restrict__ ws_gp,
    float* __restrict__ d_out) {
  __shared__ unsigned short smem[2 * BUFU + 3 * 6144];   // 119808 B

  int tid  = threadIdx.x;
  int lane = tid & 63;
  int wv   = tid >> 6;       // wave 0..7
  int n15  = lane & 15;
  int kq   = lane >> 4;
  int gx0 = blockIdx.x * 32, gy0 = blockIdx.y * 16;

  // --- A staging: 720 units (co8[4] x row[18] x qx[10]); thread t<360 handles
  //     unit t (sub-stage A: co8 0..1) and t+360 (sub-stage B: co8 2..3).
  bool ustage = tid < 360;
  int u    = ustage ? tid : 0;
  int co8  = u / 180;                 // 0..1
  int rem  = u - co8 * 180;
  int row  = rem / 10;                // 0..17
  int qx   = rem - row * 10;          // 0..9
  int iy   = gy0 + row - 1;
  int ixq  = gx0 + 4 * qx - 4;        // 16B-aligned quad
  bool gvld = ustage && (iy >= 0) && (iy < MH) && (ixq >= 0) && (ixq + 3 < MW);
  int goffA = gvld ? (co8 * 8 * MN + iy * MW + ixq) : 0;
  int lwsA[4]; unsigned smask = 0;
  #pragma unroll
  for (int e = 0; e < 4; ++e) {
    int sx = 4 * qx - 3 + e;          // stored x index
    bool sv = ustage && (sx >= 0) && (sx < RP);
    int pixw = row * RP + (sv ? sx : 0);
    int w2 = (pixw ^ (pixw >> 2)) & 3;
    int q  = (pixw ^ row) & 1;
    lwsA[e] = (pixw >> 1) * 64 + ((co8 ^ w2) << 4) + q * 8;
    if (sv) smask |= (1u << e);
  }
  // sub-stage B differs only by co8+2: lwsB[e] = lwsA[e] ^ 32, goffB = goffA + 16*MN

  // --- A-frag LDS read offsets: packed (o_row0 | o_row1<<16); +512 = x-half ---
  unsigned lrdp[9];
  #pragma unroll
  for (int t = 0; t < 9; ++t) {
    int ty = t / 3, tx = t - ty * 3;
    int sr0 = 2 * wv + ty;            // stored row for subtiles 0,1
    int pix0 = sr0 * RP + n15 + tx;
    int w20 = (pix0 ^ (pix0 >> 2)) & 3;
    int q0  = (pix0 ^ sr0) & 1;
    unsigned o0 = (pix0 >> 1) * 64 + ((kq ^ w20) << 4) + q0 * 8;
    int sr1 = sr0 + 1;                // subtiles 2,3
    int pix1 = sr1 * RP + n15 + tx;
    int w21 = (pix1 ^ (pix1 >> 2)) & 3;
    int q1  = (pix1 ^ sr1) & 1;
    unsigned o1 = (pix1 >> 1) * 64 + ((kq ^ w21) << 4) + q1 * 8;
    lrdp[t] = o0 | (o1 << 16);
  }

  // --- prologue: full stage of tile 0 into buf0; W groups 0,1 ---
  {
    f32x4 dq[8];
    if (ustage) {
      const float* sp = out0 + goffA;
      #pragma unroll
      for (int j = 0; j < 8; ++j) dq[j] = *(const f32x4*)(sp + j * MN);
    }
    stage_store8(smem, dq, gvld, lwsA, smask);
    if (ustage) {
      const float* sp = out0 + goffA + 16 * MN;
      #pragma unroll
      for (int j = 0; j < 8; ++j) dq[j] = *(const f32x4*)(sp + j * MN);
    }
    {
      int lwsB[4];
      #pragma unroll
      for (int e = 0; e < 4; ++e) lwsB[e] = lwsA[e] ^ 32;
      stage_store8(smem, dq, gvld, lwsB, smask);
    }
  }
  __builtin_amdgcn_sched_barrier(0);
  STAGE_W3(0, 0);
  STAGE_W3(1, 1);
  if (wv == 7) asm volatile("s_waitcnt vmcnt(12)" ::: "memory");
  PIPE_BARRIER();

  f32x4 acc[4][4];
  #pragma unroll
  for (int i = 0; i < 4; ++i)
    #pragma unroll
    for (int nt = 0; nt < 4; ++nt)
      acc[i][nt] = (f32x4){0.f, 0.f, 0.f, 0.f};

  #pragma unroll 1
  for (int g = 0; g < 8; ++g) {
    const unsigned short* cur = smem + (g & 1) * BUFU;
    unsigned short*       nxt = smem + ((g + 1) & 1) * BUFU;
    const float*          src = out0 + (g + 1) * (32 * MN);
    f32x4 dq[8];

    // ---- phase 0: issue subA(g+1) | W issue grp 3g+2 -> buf2 | taps 0-2
    STAGE_W3(3 * g + 2, 2);
    if (g < 7 && ustage) {
      const float* sp = src + goffA;
      #pragma unroll
      for (int j = 0; j < 8; ++j) dq[j] = *(const f32x4*)(sp + j * MN);
    }
    __builtin_amdgcn_sched_barrier(0);
    TAPS3(0)
    if (wv == 7) asm volatile("s_waitcnt vmcnt(12)" ::: "memory");
    PIPE_BARRIER();

    // ---- phase 1: store subA | issue subB(g+1) | W grp 3g+3 -> buf0 | taps 3-5
    STAGE_W3(3 * g + 3, 0);
    if (g < 7) stage_store8(nxt, dq, gvld, lwsA, smask);
    if (g < 7 && ustage) {
      const float* sp = src + goffA + 16 * MN;
      #pragma unroll
      for (int j = 0; j < 8; ++j) dq[j] = *(const f32x4*)(sp + j * MN);
    }
    __builtin_amdgcn_sched_barrier(0);
    TAPS3(1)
    if (wv == 7) {
      if (g == 7) asm volatile("s_waitcnt vmcnt(0)" ::: "memory");
      else        asm volatile("s_waitcnt vmcnt(12)" ::: "memory");
    }
    PIPE_BARRIER();

    // ---- phase 2: store subB | W grp 3g+4 -> buf1 | taps 6-8
    STAGE_W3(3 * g + 4, 1);
    if (g < 7) {
      int lwsB[4];
      #pragma unroll
      for (int e = 0; e < 4; ++e) lwsB[e] = lwsA[e] ^ 32;
      stage_store8(nxt, dq, gvld, lwsB, smask);
    }
    __builtin_amdgcn_sched_barrier(0);
    TAPS3(2)
    if (wv == 7) {
      if (g == 7) asm volatile("s_waitcnt vmcnt(0)" ::: "memory");
      else        asm volatile("s_waitcnt vmcnt(12)" ::: "memory");
    }
    PIPE_BARRIER();
  }

  // --- epilogue: bias+relu, acc -> LDS [pixel][channel] bf16 (512 x 66) ---
  #define ES 66
  {
    float bias[4];
    #pragma unroll
    for (int nt = 0; nt < 4; ++nt) bias[nt] = mb_b[nt * 16 + n15];
    #pragma unroll
    for (int i = 0; i < 4; ++i) {
      int pbase = (2 * wv + (i >> 1)) * 32 + (i & 1) * 16;
      #pragma unroll
      for (int nt = 0; nt < 4; ++nt)
        #pragma unroll
        for (int reg = 0; reg < 4; ++reg) {
          float vv = fmaxf(acc[i][nt][reg] + bias[nt], 0.f);
          smem[(pbase + kq * 4 + reg) * ES + nt * 16 + n15] = f2bf(vv);
        }
    }
  }
  __syncthreads();

  // dynamic heads: 2 passes of 256 px; thread (p, half) -> pixel, ch-half
  int p = tid & 255, hh = tid >> 8;
  int ob = hh * 32;
  float* pf = (float*)smem + 16896;   // byte 67584, past 512x66 table
  #pragma unroll 1
  for (int ps = 0; ps < 2; ++ps) {
    int pixel = ps * 256 + p;
    float mres[4] = {0.f, 0.f, 0.f, 0.f};
    float rres[4] = {0.f, 0.f, 0.f, 0.f};
    #pragma unroll 8
    for (int o = 0; o < 32; ++o) {
      float v = b2f(smem[pixel * ES + ob + o]);
      #pragma unroll
      for (int i = 0; i < 4; ++i) {
        mres[i] += ws_gp[i * NP + ob + o] * v;
        rres[i] += ws_gp[i * NP + 67 + ob + o] * v;
      }
    }
    if (hh) {
      #pragma unroll
      for (int i = 0; i < 4; ++i) { pf[p * 8 + i] = mres[i]; pf[p * 8 + 4 + i] = rres[i]; }
    }
    __syncthreads();
    if (!hh) {
      int r = pixel >> 5, xcol = pixel & 31;
      int gy = gy0 + r, gx = gx0 + xcol;
      float xc = -1.f + (2.f / 479.f) * (float)gx;
      float yc = -1.f + (2.f / 271.f) * (float)gy;
      int pix = gy * MW + gx;
      #pragma unroll
      for (int i = 0; i < 4; ++i) {
        const float* gp = ws_gp + i * NP;
        d_out[MASK_OFF + i * MN + pix] = mres[i] + pf[p * 8 + i]     + gp[66]  + gp[64]  * xc + gp[65]  * yc;
        d_out[REG_OFF  + i * MN + pix] = rres[i] + pf[p * 8 + 4 + i] + gp[133] + gp[131] * xc + gp[132] * yc;
      }
    }
    __syncthreads();
  }
}

// ------------------------------------------------------------------
// K5: feat_range MLP (1920 blocks x 64 threads)
// ------------------------------------------------------------------
__global__ void k_mlp(const float* __restrict__ masks0, const float* __restrict__ w1,
                      const float* __restrict__ b1, const float* __restrict__ w2,
                      const float* __restrict__ b2, float* __restrict__ d_out) {
  int blk = blockIdx.x;          // i*480 + w
  int i = blk / MW;
  int w = blk - i * MW;
  int k = threadIdx.x;           // 0..63
  const float* mcol = masks0 + i * MN + w;
  float s = b1[k];
  #pragma unroll 4
  for (int h = 0; h < MH; ++h) s += mcol[h * MW] * w1[h * HID + k];
  s = fmaxf(s, 0.f);
  float o0 = s * w2[k * 2 + 0];
  float o1 = s * w2[k * 2 + 1];
  #pragma unroll
  for (int off = 32; off >= 1; off >>= 1) {
    o0 += __shfl_down(o0, off);
    o1 += __shfl_down(o1, off);
  }
  if (k == 0) {
    d_out[FEAT_OFF + blk * 2 + 0] = o0 + b2[0];
    d_out[FEAT_OFF + blk * 2 + 1] = o1 + b2[1];
  }
}

// ------------------------------------------------------------------
extern "C" void kernel_launch(void* const* d_in, const int* in_sizes, int n_in,
                              void* d_out, int out_size, void* d_ws, size_t ws_size,
                              hipStream_t stream) {
  const float* out0     = (const float*)d_in[0];
  const float* out1     = (const float*)d_in[1];
  const float* hm_w     = (const float*)d_in[2];
  const float* hm_b     = (const float*)d_in[3];
  const float* params_w = (const float*)d_in[4];
  const float* params_b = (const float*)d_in[5];
  const float* mb_w     = (const float*)d_in[6];
  const float* mb_b     = (const float*)d_in[7];
  const float* mlp_w1   = (const float*)d_in[8];
  const float* mlp_b1   = (const float*)d_in[9];
  const float* mlp_w2   = (const float*)d_in[10];
  const float* mlp_b2   = (const float*)d_in[11];

  float* ws      = (float*)d_ws;
  float* ws_hm   = ws + WS_HM;
  float* candv   = ws + WS_CV;
  int*   candi   = (int*)(ws + WS_CI);
  float* ws_gp   = ws + WS_GP;
  unsigned short* ws_wt = (unsigned short*)(ws + WS_WT_F);
  float* out     = (float*)d_out;

  k_prep<<<1086, 256, 0, stream>>>(mb_w, ws_wt, out1, hm_w, hm_b, ws_hm);
  k_nms_top<<<128, 256, 0, stream>>>(ws_hm, candv, candi);
  k_gen<<<NI, 256, 0, stream>>>(candv, candi, out1, params_w, params_b, ws_gp, out);
  dim3 gconv(MW / 32, MH / 16);   // 15 x 17
  k_conv_mfma<<<gconv, 512, 0, stream>>>(out0, ws_wt, mb_b, ws_gp, out);
  k_mlp<<<NI * MW, 64, 0, stream>>>(out + MASK_OFF, mlp_w1, mlp_b1, mlp_w2, mlp_b2, out);
}

// Round 5
// 307.155 us; speedup vs baseline: 1.2484x; 1.0143x over previous
//
#include <hip/hip_runtime.h>
#include <math.h>
#include <limits.h>

// ---- problem constants ----
#define C_IN 256
#define HM_H 136
#define HM_W 240
#define HM_N (HM_H * HM_W)      // 32640
#define MB   64
#define MH   272
#define MW   480
#define MN   (MH * MW)          // 130560
#define NP   134
#define NI   4
#define HID  64

// d_out layout (floats): scores[4] | inds[4] | regs0[4*MN] | masks0[4*MN] | feat[4*480*2]
#define REG_OFF   8
#define MASK_OFF  (8 + NI * MN)
#define FEAT_OFF  (8 + 2 * NI * MN)

// ws layout (floats): hm[32640] | cand_v[512]+cand_i[512] | gp[536] | wt @ 65824
#define WS_HM   0
#define WS_CV   HM_N
#define WS_CI   (HM_N + 512)
#define WS_GP   (2 * HM_N)
#define WS_WT_F 65824

typedef float  f32x4  __attribute__((ext_vector_type(4)));
typedef short  bf16x8 __attribute__((ext_vector_type(8)));
typedef unsigned short u16x8 __attribute__((ext_vector_type(8)));

__device__ __forceinline__ unsigned short f2bf(float f) {
  unsigned int u = __float_as_uint(f);
  u += 0x7FFFu + ((u >> 16) & 1u);
  return (unsigned short)(u >> 16);
}
__device__ __forceinline__ float b2f(unsigned short h) {
  return __uint_as_float(((unsigned int)h) << 16);
}

__device__ __forceinline__ void glds16(const void* g, void* l) {
  __builtin_amdgcn_global_load_lds(
      (const __attribute__((address_space(1))) unsigned int*)g,
      (__attribute__((address_space(3))) unsigned int*)l, 16, 0, 0);
}

// ------------------------------------------------------------------
// K0: merged weight-prep + heatmap.
// ------------------------------------------------------------------
__global__ void k_prep(const float* __restrict__ mb_w, unsigned short* __restrict__ wt,
                       const float* __restrict__ out1, const float* __restrict__ hm_w,
                       const float* __restrict__ hm_b, float* __restrict__ ws_hm) {
  __shared__ float part[4][64];
  if (blockIdx.x < 576) {
    int idx = blockIdx.x * 256 + threadIdx.x;     // 147456 total
    int j    = idx & 7;
    int lane = (idx >> 3) & 63;
    int nt   = (idx >> 9) & 3;
    int gt   = idx >> 11;
    int t    = gt % 9;
    int g    = gt / 9;
    int n = nt * 16 + (lane & 15);
    int c = g * 32 + (lane >> 4) * 8 + j;
    wt[idx] = f2bf(mb_w[(n * C_IN + c) * 9 + t]);
  } else {
    int b = blockIdx.x - 576, t = threadIdx.x;
    int cg = t >> 6, pl = t & 63;
    int p = b * 64 + pl;                         // 510*64 = 32640
    float s = 0.f;
    #pragma unroll 16
    for (int c = 0; c < 64; ++c)
      s += hm_w[cg * 64 + c] * out1[(cg * 64 + c) * HM_N + p];
    part[cg][pl] = s;
    __syncthreads();
    if (t < 64) {
      float tot = part[0][t] + part[1][t] + part[2][t] + part[3][t] + hm_b[0];
      float sig = 1.f / (1.f + expf(-tot));
      sig = fminf(fmaxf(sig, 1e-4f), 1.f - 1e-4f);
      ws_hm[b * 64 + t] = sig;
    }
  }
}

// ------------------------------------------------------------------
// top-4 list merge helpers
// ------------------------------------------------------------------
__device__ __forceinline__ bool better(float av, int ai, float bv, int bi) {
  return (av > bv) || (av == bv && ai < bi);
}

template<int NTHR>
__device__ void top4_tree(float* sv, int* si, int t) {
  for (int s = NTHR / 2; s >= 1; s >>= 1) {
    if (t < s) {
      float a[4], b[4]; int ai[4], bj[4];
      #pragma unroll
      for (int k = 0; k < 4; ++k) {
        a[k] = sv[t * 4 + k];        ai[k] = si[t * 4 + k];
        b[k] = sv[(t + s) * 4 + k];  bj[k] = si[(t + s) * 4 + k];
      }
      float ov[4]; int oi[4];
      int i = 0, j = 0;
      #pragma unroll
      for (int k = 0; k < 4; ++k) {
        if (better(a[i], ai[i], b[j], bj[j])) { ov[k] = a[i]; oi[k] = ai[i]; ++i; }
        else                                   { ov[k] = b[j]; oi[k] = bj[j]; ++j; }
      }
      #pragma unroll
      for (int k = 0; k < 4; ++k) { sv[t * 4 + k] = ov[k]; si[t * 4 + k] = oi[k]; }
    }
    __syncthreads();
  }
}

// ------------------------------------------------------------------
// K2a: fused NMS + per-block top-4 (128 blocks x 255 pixels)
// ------------------------------------------------------------------
__global__ void k_nms_top(const float* __restrict__ ws_hm, float* __restrict__ candv,
                          int* __restrict__ candi) {
  __shared__ float sv[256 * 4];
  __shared__ int   si[256 * 4];
  int b = blockIdx.x, t = threadIdx.x;
  float v = -1.f; int idx = INT_MAX;
  if (t < 255) {
    int p = b * 255 + t;
    int y = p / HM_W, x = p - y * HM_W;
    float c = ws_hm[p], m = c;
    #pragma unroll
    for (int dy = -1; dy <= 1; ++dy)
      #pragma unroll
      for (int dx = -1; dx <= 1; ++dx) {
        int yy = y + dy, xx = x + dx;
        if (yy >= 0 && yy < HM_H && xx >= 0 && xx < HM_W)
          m = fmaxf(m, ws_hm[yy * HM_W + xx]);
      }
    v = (c == m) ? c : 0.f;
    idx = p;
  }
  sv[t * 4] = v; si[t * 4] = idx;
  #pragma unroll
  for (int k = 1; k < 4; ++k) { sv[t * 4 + k] = -1.f; si[t * 4 + k] = INT_MAX; }
  __syncthreads();
  top4_tree<256>(sv, si, t);
  if (t == 0) {
    #pragma unroll
    for (int k = 0; k < 4; ++k) { candv[b * 4 + k] = sv[k]; candi[b * 4 + k] = si[k]; }
  }
}

// ------------------------------------------------------------------
// K3: redundant final top-k merge + gen_params. Block i -> instance i.
// ------------------------------------------------------------------
__global__ void k_gen(const float* __restrict__ candv, const int* __restrict__ candi,
                      const float* __restrict__ out1, const float* __restrict__ params_w,
                      const float* __restrict__ params_b, float* __restrict__ ws_gp,
                      float* __restrict__ d_out) {
  __shared__ float sv[128 * 4];
  __shared__ int   si[128 * 4];
  __shared__ float col[C_IN];
  int t = threadIdx.x, i = blockIdx.x;
  if (t < 128) {
    #pragma unroll
    for (int k = 0; k < 4; ++k) { sv[t * 4 + k] = candv[t * 4 + k]; si[t * 4 + k] = candi[t * 4 + k]; }
  }
  __syncthreads();
  top4_tree<128>(sv, si, t);
  if (i == 0 && t < 4) {
    d_out[t]     = sv[t];
    d_out[4 + t] = (float)si[t];
  }
  int p = si[i];
  col[t] = out1[t * HM_N + p];
  __syncthreads();
  if (t < NP) {
    float s = params_b[t];
    #pragma unroll 8
    for (int c = 0; c < C_IN; ++c) s += params_w[t * C_IN + c] * col[c];
    ws_gp[i * NP + t] = s;
  }
}

// ------------------------------------------------------------------
// K4 v6: wave = 64px x 64ch, block 16x32 px; producer-specialized W path.
//  NEW vs v5:
//   - XCD-chunked column-major block swizzle (y-adjacent tiles share an
//     XCD L2 -> halo rows fetched once per XCD)
//   - deep A-issue: subA(g+2) issued at P0(g), subB(g+2) at P1(g);
//     stores of tile g+1 happen 5 phases after issue -> zero store stall,
//     smooth HBM issue. Costs 64 staging VGPRs; free at 2 waves/SIMD
//     (__launch_bounds__(512,2) -> 256-VGPR budget).
// LDS: A 2x41472B + W 3x12288B = 119808 B -> 1 block/CU.
// ------------------------------------------------------------------
#define SR   18                 // stored rows (16 + 2 halo)
#define RP   36                 // stored x positions per row (gx0-1 .. gx0+34)
#define BUFU (SR * RP * 32)     // 20736 ushorts = 41472 B per A buffer
#define WOFF (2 * BUFU)         // ushort idx 41472; W bufs: +b*6144 ushorts

#define PIPE_BARRIER() do {                                   \
    __builtin_amdgcn_sched_barrier(0);                        \
    asm volatile("s_waitcnt lgkmcnt(0)" ::: "memory");        \
    __builtin_amdgcn_s_barrier();                             \
    __builtin_amdgcn_sched_barrier(0);                        \
  } while (0)

// stage weight group G (3 taps = 12288B) into W buf B; wave 7 only
#define STAGE_W3(G, B)                                                    \
  if (wv == 7 && (G) < 24) {                                              \
    const char* wsrc = (const char*)wt + (G) * 12288 + lane * 16;         \
    char* wdst = (char*)smem + 2 * WOFF + (B) * 12288;                    \
    _Pragma("unroll")                                                     \
    for (int i_ = 0; i_ < 12; ++i_)                                       \
      glds16(wsrc + i_ * 1024, wdst + i_ * 1024);                         \
  }

#define MFMA16(A, B, C) __builtin_amdgcn_mfma_f32_16x16x32_bf16(A, B, C, 0, 0, 0)

#define TAPS3(P) {                                                        \
    const unsigned short* wl = smem + WOFF + (P) * 6144 + lane * 8;       \
    _Pragma("unroll")                                                     \
    for (int tt = 0; tt < 3; ++tt) {                                      \
      bf16x8 bb0 = *(const bf16x8*)(wl + tt * 2048);                      \
      bf16x8 bb1 = *(const bf16x8*)(wl + tt * 2048 + 512);                \
      bf16x8 bb2 = *(const bf16x8*)(wl + tt * 2048 + 1024);               \
      bf16x8 bb3 = *(const bf16x8*)(wl + tt * 2048 + 1536);               \
      unsigned pk = lrdp[(P) * 3 + tt];                                   \
      const unsigned short* c0 = cur + (pk & 0xFFFFu);                    \
      const unsigned short* c1 = cur + (pk >> 16);                        \
      bf16x8 a0 = *(const bf16x8*)c0;                                     \
      bf16x8 a1 = *(const bf16x8*)(c0 + 512);                             \
      bf16x8 a2 = *(const bf16x8*)c1;                                     \
      bf16x8 a3 = *(const bf16x8*)(c1 + 512);                             \
      acc[0][0] = MFMA16(a0, bb0, acc[0][0]);                             \
      acc[0][1] = MFMA16(a0, bb1, acc[0][1]);                             \
      acc[0][2] = MFMA16(a0, bb2, acc[0][2]);                             \
      acc[0][3] = MFMA16(a0, bb3, acc[0][3]);                             \
      acc[1][0] = MFMA16(a1, bb0, acc[1][0]);                             \
      acc[1][1] = MFMA16(a1, bb1, acc[1][1]);                             \
      acc[1][2] = MFMA16(a1, bb2, acc[1][2]);                             \
      acc[1][3] = MFMA16(a1, bb3, acc[1][3]);                             \
      acc[2][0] = MFMA16(a2, bb0, acc[2][0]);                             \
      acc[2][1] = MFMA16(a2, bb1, acc[2][1]);                             \
      acc[2][2] = MFMA16(a2, bb2, acc[2][2]);                             \
      acc[2][3] = MFMA16(a2, bb3, acc[2][3]);                             \
      acc[3][0] = MFMA16(a3, bb0, acc[3][0]);                             \
      acc[3][1] = MFMA16(a3, bb1, acc[3][1]);                             \
      acc[3][2] = MFMA16(a3, bb2, acc[3][2]);                             \
      acc[3][3] = MFMA16(a3, bb3, acc[3][3]);                             \
    } }

__device__ __forceinline__ void stage_store8(unsigned short* buf, const f32x4* dq,
                                             bool gv, const int* lw, unsigned sm) {
  #pragma unroll
  for (int e = 0; e < 4; ++e) if ((sm >> e) & 1u) {
    u16x8 v;
    #pragma unroll
    for (int j = 0; j < 8; ++j) v[j] = f2bf(gv ? dq[j][e] : 0.f);
    *(u16x8*)(buf + lw[e]) = v;
  }
}

__global__ __launch_bounds__(512, 2) void k_conv_mfma(
    const float* __restrict__ out0, const unsigned short* __restrict__ wt,
    const float* __restrict__ mb_b, const float* __restrict__ ws_gp,
    float* __restrict__ d_out) {
  __shared__ unsigned short smem[2 * BUFU + 3 * 6144];   // 119808 B

  int tid  = threadIdx.x;
  int lane = tid & 63;
  int wv   = tid >> 6;       // wave 0..7
  int n15  = lane & 15;
  int kq   = lane >> 4;

  // --- XCD-chunked bijective swizzle (nwg=255, 8 XCDs: q=31, r=7) ---
  // then column-major within chunk: consecutive wgid = y-adjacent tiles.
  int orig = blockIdx.x;
  int xcd  = orig & 7, pos = orig >> 3;
  int wgid = (xcd < 7) ? (xcd * 32 + pos) : (224 + pos);
  int bx = wgid / 17, by = wgid - bx * 17;
  int gx0 = bx * 32, gy0 = by * 16;

  // --- A staging: 720 units (co8[4] x row[18] x qx[10]); thread t<360 handles
  //     unit t (sub-stage A: co8 0..1) and t+360 (sub-stage B: co8 2..3).
  bool ustage = tid < 360;
  int u    = ustage ? tid : 0;
  int co8  = u / 180;                 // 0..1
  int rem  = u - co8 * 180;
  int row  = rem / 10;                // 0..17
  int qx   = rem - row * 10;          // 0..9
  int iy   = gy0 + row - 1;
  int ixq  = gx0 + 4 * qx - 4;        // 16B-aligned quad
  bool gvld = ustage && (iy >= 0) && (iy < MH) && (ixq >= 0) && (ixq + 3 < MW);
  int goffA = gvld ? (co8 * 8 * MN + iy * MW + ixq) : 0;
  int lwsA[4]; unsigned smask = 0;
  #pragma unroll
  for (int e = 0; e < 4; ++e) {
    int sx = 4 * qx - 3 + e;          // stored x index
    bool sv = ustage && (sx >= 0) && (sx < RP);
    int pixw = row * RP + (sv ? sx : 0);
    int w2 = (pixw ^ (pixw >> 2)) & 3;
    int q  = (pixw ^ row) & 1;
    lwsA[e] = (pixw >> 1) * 64 + ((co8 ^ w2) << 4) + q * 8;
    if (sv) smask |= (1u << e);
  }
  // sub-stage B: lwsB[e] = lwsA[e] ^ 32, goffB = goffA + 16*MN

  // --- A-frag LDS read offsets: packed (o_row0 | o_row1<<16); +512 = x-half ---
  unsigned lrdp[9];
  #pragma unroll
  for (int t = 0; t < 9; ++t) {
    int ty = t / 3, tx = t - ty * 3;
    int sr0 = 2 * wv + ty;            // stored row for subtiles 0,1
    int pix0 = sr0 * RP + n15 + tx;
    int w20 = (pix0 ^ (pix0 >> 2)) & 3;
    int q0  = (pix0 ^ sr0) & 1;
    unsigned o0 = (pix0 >> 1) * 64 + ((kq ^ w20) << 4) + q0 * 8;
    int sr1 = sr0 + 1;                // subtiles 2,3
    int pix1 = sr1 * RP + n15 + tx;
    int w21 = (pix1 ^ (pix1 >> 2)) & 3;
    int q1  = (pix1 ^ sr1) & 1;
    unsigned o1 = (pix1 >> 1) * 64 + ((kq ^ w21) << 4) + q1 * 8;
    lrdp[t] = o0 | (o1 << 16);
  }

  // --- prologue: stage tile0 fully into buf0; issue tile1 subA+subB;
  //     stage W groups 0,1 ---
  f32x4 dqA[8], dqB[8];
  if (ustage) {
    const float* sp = out0 + goffA;
    #pragma unroll
    for (int j = 0; j < 8; ++j) dqA[j] = *(const f32x4*)(sp + j * MN);
  }
  stage_store8(smem, dqA, gvld, lwsA, smask);
  if (ustage) {
    const float* sp = out0 + goffA + 16 * MN;
    #pragma unroll
    for (int j = 0; j < 8; ++j) dqB[j] = *(const f32x4*)(sp + j * MN);
  }
  {
    int lwsB[4];
    #pragma unroll
    for (int e = 0; e < 4; ++e) lwsB[e] = lwsA[e] ^ 32;
    stage_store8(smem, dqB, gvld, lwsB, smask);
  }
  __builtin_amdgcn_sched_barrier(0);
  if (ustage) {
    const float* sp = out0 + 32 * MN + goffA;          // tile1 subA
    #pragma unroll
    for (int j = 0; j < 8; ++j) dqA[j] = *(const f32x4*)(sp + j * MN);
    const float* sq = out0 + 32 * MN + goffA + 16 * MN; // tile1 subB
    #pragma unroll
    for (int j = 0; j < 8; ++j) dqB[j] = *(const f32x4*)(sq + j * MN);
  }
  __builtin_amdgcn_sched_barrier(0);
  STAGE_W3(0, 0);
  STAGE_W3(1, 1);
  if (wv == 7) asm volatile("s_waitcnt vmcnt(12)" ::: "memory");
  PIPE_BARRIER();

  f32x4 acc[4][4];
  #pragma unroll
  for (int i = 0; i < 4; ++i)
    #pragma unroll
    for (int nt = 0; nt < 4; ++nt)
      acc[i][nt] = (f32x4){0.f, 0.f, 0.f, 0.f};

  #pragma unroll 1
  for (int g = 0; g < 8; ++g) {
    const unsigned short* cur = smem + (g & 1) * BUFU;
    unsigned short*       nxt = smem + ((g + 1) & 1) * BUFU;

    // ---- phase 0: store subA(g+1) [issued 5 phases ago] | issue subA(g+2)
    //               | W grp 3g+2 -> buf2 | taps 0-2
    STAGE_W3(3 * g + 2, 2);
    if (g < 7) stage_store8(nxt, dqA, gvld, lwsA, smask);
    __builtin_amdgcn_sched_barrier(0);
    if (g < 6 && ustage) {
      const float* sp = out0 + (g + 2) * (32 * MN) + goffA;
      #pragma unroll
      for (int j = 0; j < 8; ++j) dqA[j] = *(const f32x4*)(sp + j * MN);
    }
    __builtin_amdgcn_sched_barrier(0);
    TAPS3(0)
    if (wv == 7) asm volatile("s_waitcnt vmcnt(12)" ::: "memory");
    PIPE_BARRIER();

    // ---- phase 1: store subB(g+1) | issue subB(g+2) | W grp 3g+3 -> buf0
    //               | taps 3-5
    STAGE_W3(3 * g + 3, 0);
    if (g < 7) {
      int lwsB[4];
      #pragma unroll
      for (int e = 0; e < 4; ++e) lwsB[e] = lwsA[e] ^ 32;
      stage_store8(nxt, dqB, gvld, lwsB, smask);
    }
    __builtin_amdgcn_sched_barrier(0);
    if (g < 6 && ustage) {
      const float* sp = out0 + (g + 2) * (32 * MN) + goffA + 16 * MN;
      #pragma unroll
      for (int j = 0; j < 8; ++j) dqB[j] = *(const f32x4*)(sp + j * MN);
    }
    __builtin_amdgcn_sched_barrier(0);
    TAPS3(1)
    if (wv == 7) {
      if (g == 7) asm volatile("s_waitcnt vmcnt(0)" ::: "memory");
      else        asm volatile("s_waitcnt vmcnt(12)" ::: "memory");
    }
    PIPE_BARRIER();

    // ---- phase 2: W grp 3g+4 -> buf1 | taps 6-8
    STAGE_W3(3 * g + 4, 1);
    TAPS3(2)
    if (wv == 7) {
      if (g == 7) asm volatile("s_waitcnt vmcnt(0)" ::: "memory");
      else        asm volatile("s_waitcnt vmcnt(12)" ::: "memory");
    }
    PIPE_BARRIER();
  }

  // --- epilogue: bias+relu, acc -> LDS [pixel][channel] bf16 (512 x 66) ---
  #define ES 66
  {
    float bias[4];
    #pragma unroll
    for (int nt = 0; nt < 4; ++nt) bias[nt] = mb_b[nt * 16 + n15];
    #pragma unroll
    for (int i = 0; i < 4; ++i) {
      int pbase = (2 * wv + (i >> 1)) * 32 + (i & 1) * 16;
      #pragma unroll
      for (int nt = 0; nt < 4; ++nt)
        #pragma unroll
        for (int reg = 0; reg < 4; ++reg) {
          float vv = fmaxf(acc[i][nt][reg] + bias[nt], 0.f);
          smem[(pbase + kq * 4 + reg) * ES + nt * 16 + n15] = f2bf(vv);
        }
    }
  }
  __syncthreads();

  // dynamic heads: 2 passes of 256 px; thread (p, half) -> pixel, ch-half
  int p = tid & 255, hh = tid >> 8;
  int ob = hh * 32;
  float* pf = (float*)smem + 16896;   // byte 67584, past 512x66 table
  #pragma unroll 1
  for (int ps = 0; ps < 2; ++ps) {
    int pixel = ps * 256 + p;
    float mres[4] = {0.f, 0.f, 0.f, 0.f};
    float rres[4] = {0.f, 0.f, 0.f, 0.f};
    #pragma unroll 8
    for (int o = 0; o < 32; ++o) {
      float v = b2f(smem[pixel * ES + ob + o]);
      #pragma unroll
      for (int i = 0; i < 4; ++i) {
        mres[i] += ws_gp[i * NP + ob + o] * v;
        rres[i] += ws_gp[i * NP + 67 + ob + o] * v;
      }
    }
    if (hh) {
      #pragma unroll
      for (int i = 0; i < 4; ++i) { pf[p * 8 + i] = mres[i]; pf[p * 8 + 4 + i] = rres[i]; }
    }
    __syncthreads();
    if (!hh) {
      int r = pixel >> 5, xcol = pixel & 31;
      int gy = gy0 + r, gx = gx0 + xcol;
      float xc = -1.f + (2.f / 479.f) * (float)gx;
      float yc = -1.f + (2.f / 271.f) * (float)gy;
      int pix = gy * MW + gx;
      #pragma unroll
      for (int i = 0; i < 4; ++i) {
        const float* gp = ws_gp + i * NP;
        d_out[MASK_OFF + i * MN + pix] = mres[i] + pf[p * 8 + i]     + gp[66]  + gp[64]  * xc + gp[65]  * yc;
        d_out[REG_OFF  + i * MN + pix] = rres[i] + pf[p * 8 + 4 + i] + gp[133] + gp[131] * xc + gp[132] * yc;
      }
    }
    __syncthreads();
  }
}

// ------------------------------------------------------------------
// K5: feat_range MLP (1920 blocks x 64 threads)
// ------------------------------------------------------------------
__global__ void k_mlp(const float* __restrict__ masks0, const float* __restrict__ w1,
                      const float* __restrict__ b1, const float* __restrict__ w2,
                      const float* __restrict__ b2, float* __restrict__ d_out) {
  int blk = blockIdx.x;          // i*480 + w
  int i = blk / MW;
  int w = blk - i * MW;
  int k = threadIdx.x;           // 0..63
  const float* mcol = masks0 + i * MN + w;
  float s = b1[k];
  #pragma unroll 4
  for (int h = 0; h < MH; ++h) s += mcol[h * MW] * w1[h * HID + k];
  s = fmaxf(s, 0.f);
  float o0 = s * w2[k * 2 + 0];
  float o1 = s * w2[k * 2 + 1];
  #pragma unroll
  for (int off = 32; off >= 1; off >>= 1) {
    o0 += __shfl_down(o0, off);
    o1 += __shfl_down(o1, off);
  }
  if (k == 0) {
    d_out[FEAT_OFF + blk * 2 + 0] = o0 + b2[0];
    d_out[FEAT_OFF + blk * 2 + 1] = o1 + b2[1];
  }
}

// ------------------------------------------------------------------
extern "C" void kernel_launch(void* const* d_in, const int* in_sizes, int n_in,
                              void* d_out, int out_size, void* d_ws, size_t ws_size,
                              hipStream_t stream) {
  const float* out0     = (const float*)d_in[0];
  const float* out1     = (const float*)d_in[1];
  const float* hm_w     = (const float*)d_in[2];
  const float* hm_b     = (const float*)d_in[3];
  const float* params_w = (const float*)d_in[4];
  const float* params_b = (const float*)d_in[5];
  const float* mb_w     = (const float*)d_in[6];
  const float* mb_b     = (const float*)d_in[7];
  const float* mlp_w1   = (const float*)d_in[8];
  const float* mlp_b1   = (const float*)d_in[9];
  const float* mlp_w2   = (const float*)d_in[10];
  const float* mlp_b2   = (const float*)d_in[11];

  float* ws      = (float*)d_ws;
  float* ws_hm   = ws + WS_HM;
  float* candv   = ws + WS_CV;
  int*   candi   = (int*)(ws + WS_CI);
  float* ws_gp   = ws + WS_GP;
  unsigned short* ws_wt = (unsigned short*)(ws + WS_WT_F);
  float* out     = (float*)d_out;

  k_prep<<<1086, 256, 0, stream>>>(mb_w, ws_wt, out1, hm_w, hm_b, ws_hm);
  k_nms_top<<<128, 256, 0, stream>>>(ws_hm, candv, candi);
  k_gen<<<NI, 256, 0, stream>>>(candv, candi, out1, params_w, params_b, ws_gp, out);
  k_conv_mfma<<<255, 512, 0, stream>>>(out0, ws_wt, mb_b, ws_gp, out);
  k_mlp<<<NI * MW, 64, 0, stream>>>(out + MASK_OFF, mlp_w1, mlp_b1, mlp_w2, mlp_b2, out);
}